// Round 5
// baseline (3672.808 us; speedup 1.0000x reference)
//
#include <hip/hip_runtime.h>
#include <math.h>

#define NA      128
#define NBATCH  2048
#define NIT     300
#define NBIS    40
#define LRC     0.02f
#define EPSC    1e-8f

// ---- wave64 cross-lane reductions via DPP (VALU pipe, no LDS traffic) ----
// row_shr:n = 0x110+n ; row_bcast:15 = 0x142 ; row_bcast:31 = 0x143
template <int CTRL>
__device__ __forceinline__ float dpp_sum_step(float x) {
  int s = __builtin_amdgcn_update_dpp(0, __float_as_int(x), CTRL, 0xF, 0xF, true);
  return x + __int_as_float(s);
}
__device__ __forceinline__ float wave_sum64(float x) {
  x = dpp_sum_step<0x111>(x);
  x = dpp_sum_step<0x112>(x);
  x = dpp_sum_step<0x114>(x);
  x = dpp_sum_step<0x118>(x);
  x = dpp_sum_step<0x142>(x);
  x = dpp_sum_step<0x143>(x);
  return x;  // full-wave total lands in lane 63
}
template <int CTRL>
__device__ __forceinline__ float dpp_mov_self(float x) {
  int s = __builtin_amdgcn_update_dpp(__float_as_int(x), __float_as_int(x), CTRL, 0xF, 0xF, false);
  return __int_as_float(s);
}
__device__ __forceinline__ float wave_min64(float x) {
  x = fminf(x, dpp_mov_self<0x111>(x));
  x = fminf(x, dpp_mov_self<0x112>(x));
  x = fminf(x, dpp_mov_self<0x114>(x));
  x = fminf(x, dpp_mov_self<0x118>(x));
  x = fminf(x, dpp_mov_self<0x142>(x));
  x = fminf(x, dpp_mov_self<0x143>(x));
  return x;
}
__device__ __forceinline__ float wave_max64(float x) {
  x = fmaxf(x, dpp_mov_self<0x111>(x));
  x = fmaxf(x, dpp_mov_self<0x112>(x));
  x = fmaxf(x, dpp_mov_self<0x114>(x));
  x = fmaxf(x, dpp_mov_self<0x118>(x));
  x = fmaxf(x, dpp_mov_self<0x142>(x));
  x = fmaxf(x, dpp_mov_self<0x143>(x));
  return x;
}
__device__ __forceinline__ float read_lane63(float x) {
  return __int_as_float(__builtin_amdgcn_readlane(__float_as_int(x), 63));
}
__device__ __forceinline__ float clip1(float x) {
  return __builtin_amdgcn_fmed3f(x, -1.0f, 1.0f);  // clip to [-1, 1], c = MAX_WEIGHT
}

// One block per batch element. 128 threads: thread t owns asset t.
// A-row (gamma-folded) lives in 128 VGPRs per thread; w broadcast from LDS.
//
// R2-R4 forensic: VGPR_Count pinned at 100 regardless of launch_bounds /
// waves_per_eu, WRITE_SIZE = output only (no spill stores) -> the compiler
// RE-EXECUTES the loop-invariant covmat loads inside the 300-iter loop
// (remat/sink; legal, covmat never written) instead of keeping A live.
// ~40 GB of L3-served re-reads, latency-bound, 3.6 ms.
// Fix: empty asm volatile "+v" redefines each A element as the output of an
// opaque instruction -> NOT rematerializable -> must stay register-resident
// (or visibly spill: that would show as ~134 MB in WRITE_SIZE).
__global__
__attribute__((amdgpu_flat_work_group_size(128, 128)))
__attribute__((amdgpu_waves_per_eu(1, 2)))
void markowitz_kernel(
    const float* __restrict__ rets,
    const float* __restrict__ covmat,
    const float* __restrict__ gamma,
    const float* __restrict__ alpha,
    float* __restrict__ out)
{
  const int b    = blockIdx.x;
  const int t    = threadIdx.x;
  const int lane = t & 63;
  const int wv   = t >> 6;  // wave 0 or 1

  __shared__ __align__(16) float ws[NA];   // current weights
  __shared__ __align__(16) float vs[NA];   // pre-projection vector for bisection
  __shared__ float pp[8];                  // [0..3]: w·Aw, w·w per wave; [4,5]: min; [6,7]: max
  __shared__ float tau_s;

  // ---- one-time load: A row t with gamma folded in (A = gamma * covmat) ----
  const float gm = gamma[b];
  const float4* Arow = reinterpret_cast<const float4*>(
      covmat + (size_t)b * NA * NA + (size_t)t * NA);
  float4 a[32];
#pragma unroll
  for (int k = 0; k < 32; ++k) {
    float4 q = Arow[k];
    a[k] = make_float4(q.x * gm, q.y * gm, q.z * gm, q.w * gm);
  }
  // Opaque-ify: forbid rematerialization of the A tile (see header comment).
#pragma unroll
  for (int k = 0; k < 32; ++k) {
    asm volatile("" : "+v"(a[k].x), "+v"(a[k].y), "+v"(a[k].z), "+v"(a[k].w));
  }
  const float r_t = rets[b * NA + t];
  const float av  = fabsf(alpha[b]);

  float w_t = 1.0f / NA;
  ws[t] = w_t;
  __syncthreads();

#pragma unroll 1
  for (int it = 0; it < NIT; ++it) {
    // ---- 1. Aw[t] = A[t,:] · w  (A in regs, w broadcast from LDS) ----
    const float4* ws4 = reinterpret_cast<const float4*>(ws);
    float4 acc = make_float4(0.f, 0.f, 0.f, 0.f);
#pragma unroll
    for (int k = 0; k < 32; ++k) {
      float4 wk = ws4[k];  // uniform address -> single broadcast ds_read_b128
      acc.x = fmaf(a[k].x, wk.x, acc.x);
      acc.y = fmaf(a[k].y, wk.y, acc.y);
      acc.z = fmaf(a[k].z, wk.z, acc.z);
      acc.w = fmaf(a[k].w, wk.w, acc.w);
    }
    const float Aw = (acc.x + acc.y) + (acc.z + acc.w);

    // ---- 2. risk = sqrt(w·Aw + eps), nrm = sqrt(w·w + eps) ----
    float p1 = wave_sum64(w_t * Aw);
    float p2 = wave_sum64(w_t * w_t);
    if (lane == 63) { pp[wv * 2 + 0] = p1; pp[wv * 2 + 1] = p2; }
    __syncthreads();
    const float risk = sqrtf(pp[0] + pp[2] + EPSC);
    const float nrm  = sqrtf(pp[1] + pp[3] + EPSC);

    // ---- 3. gradient ascent step ----
    const float g_t = r_t - Aw / risk - av * (w_t / nrm);
    const float v_t = w_t + LRC * g_t;
    vs[t] = v_t;
    float mn = wave_min64(v_t);
    float mx = wave_max64(v_t);
    if (lane == 63) { pp[4 + wv] = mn; pp[6 + wv] = mx; }
    __syncthreads();

    // ---- 4. bisection for tau (wave 0 only; 2 elements per lane) ----
    if (wv == 0) {
      float v0 = vs[lane];
      float v1 = vs[lane + 64];
      float lo = fminf(pp[4], pp[5]) - 2.0f;  // min(v) - c - 1
      float hi = fmaxf(pp[6], pp[7]) + 1.0f;  // max(v) + c
#pragma unroll 1
      for (int r = 0; r < NBIS; ++r) {
        const float mid = 0.5f * (lo + hi);
        float s = clip1(v0 - mid) + clip1(v1 - mid);
        s = wave_sum64(s);
        const float stot = read_lane63(s);
        const bool big = stot > 1.0f;
        lo = big ? mid : lo;
        hi = big ? hi : mid;
      }
      if (lane == 0) tau_s = 0.5f * (lo + hi);
    }
    __syncthreads();

    // ---- 5. project: w = clip(v - tau, -c, c) ----
    const float tau = tau_s;
    w_t = clip1(v_t - tau);
    ws[t] = w_t;
    __syncthreads();
  }

  out[b * NA + t] = w_t;
}

extern "C" void kernel_launch(void* const* d_in, const int* in_sizes, int n_in,
                              void* d_out, int out_size, void* d_ws, size_t ws_size,
                              hipStream_t stream) {
  const float* rets   = (const float*)d_in[0];
  const float* covmat = (const float*)d_in[1];
  const float* gamma  = (const float*)d_in[2];
  const float* alpha  = (const float*)d_in[3];
  float* out = (float*)d_out;

  hipLaunchKernelGGL(markowitz_kernel, dim3(NBATCH), dim3(NA), 0, stream,
                     rets, covmat, gamma, alpha, out);
}

// Round 6
// 2726.014 us; speedup vs baseline: 1.3473x; 1.3473x over previous
//
#include <hip/hip_runtime.h>
#include <math.h>

#define NA      128
#define NBATCH  2048
#define NTHR    256
#define NIT     300
#define NBIS    40
#define LRC     0.02f
#define EPSC    1e-8f

// ---- wave64 cross-lane reductions via DPP (VALU pipe, no LDS traffic) ----
template <int CTRL>
__device__ __forceinline__ float dpp_sum_step(float x) {
  int s = __builtin_amdgcn_update_dpp(0, __float_as_int(x), CTRL, 0xF, 0xF, true);
  return x + __int_as_float(s);
}
__device__ __forceinline__ float wave_sum64(float x) {
  x = dpp_sum_step<0x111>(x);
  x = dpp_sum_step<0x112>(x);
  x = dpp_sum_step<0x114>(x);
  x = dpp_sum_step<0x118>(x);
  x = dpp_sum_step<0x142>(x);
  x = dpp_sum_step<0x143>(x);
  return x;  // total in lane 63
}
template <int CTRL>
__device__ __forceinline__ float dpp_mov_self(float x) {
  int s = __builtin_amdgcn_update_dpp(__float_as_int(x), __float_as_int(x), CTRL, 0xF, 0xF, false);
  return __int_as_float(s);
}
__device__ __forceinline__ float wave_min64(float x) {
  x = fminf(x, dpp_mov_self<0x111>(x));
  x = fminf(x, dpp_mov_self<0x112>(x));
  x = fminf(x, dpp_mov_self<0x114>(x));
  x = fminf(x, dpp_mov_self<0x118>(x));
  x = fminf(x, dpp_mov_self<0x142>(x));
  x = fminf(x, dpp_mov_self<0x143>(x));
  return x;
}
__device__ __forceinline__ float wave_max64(float x) {
  x = fmaxf(x, dpp_mov_self<0x111>(x));
  x = fmaxf(x, dpp_mov_self<0x112>(x));
  x = fmaxf(x, dpp_mov_self<0x114>(x));
  x = fmaxf(x, dpp_mov_self<0x118>(x));
  x = fmaxf(x, dpp_mov_self<0x142>(x));
  x = fmaxf(x, dpp_mov_self<0x143>(x));
  return x;
}
__device__ __forceinline__ float read_lane63(float x) {
  return __int_as_float(__builtin_amdgcn_readlane(__float_as_int(x), 63));
}
__device__ __forceinline__ float clip1(float x) {
  return __builtin_amdgcn_fmed3f(x, -1.0f, 1.0f);  // c = MAX_WEIGHT = 1
}

// One block per batch element. 256 threads: thread (r = tid&127, h = tid>>7)
// owns HALF of row r (columns 64h..64h+63) -> A-tile = 16 float4 = 64 VGPRs.
//
// R2-R5 forensic: with 128-reg A-tiles the allocator pins VGPR_Count at ~100
// (its ~5 waves/EU heuristic) and spills/remats the tile regardless of
// __launch_bounds__, amdgpu_waves_per_eu(1,2), or opaque-asm pinning ->
// ~39 GB of L2/L3-served re-reads per dispatch, 3.6 ms. Fix: make per-thread
// demand (~64 A + ~30 working) FIT the heuristic budget instead of fighting it.
__global__ __launch_bounds__(NTHR)
__attribute__((amdgpu_waves_per_eu(1, 4)))
void markowitz_kernel(
    const float* __restrict__ rets,
    const float* __restrict__ covmat,
    const float* __restrict__ gamma,
    const float* __restrict__ alpha,
    float* __restrict__ out)
{
  const int b    = blockIdx.x;
  const int tid  = threadIdx.x;
  const int r    = tid & (NA - 1);  // row 0..127
  const int h    = tid >> 7;        // half 0/1
  const int lane = tid & 63;
  const int wv   = tid >> 6;        // wave 0..3

  __shared__ __align__(16) float ws[NA];      // current weights
  __shared__ __align__(16) float vs[NA];      // pre-projection vector
  __shared__ float partial[NTHR];             // half-row dot partials
  __shared__ float pp[8];                     // [0..3] wAw,ww per wave; [4,5] min; [6,7] max
  __shared__ float tau_s;

  // ---- one-time load: half-row of A with gamma folded in ----
  const float gm = gamma[b];
  const float4* Ar = reinterpret_cast<const float4*>(
      covmat + (size_t)b * NA * NA + (size_t)r * NA + (size_t)h * 64);
  float4 a[16];
#pragma unroll
  for (int k = 0; k < 16; ++k) {
    float4 q = Ar[k];
    a[k] = make_float4(q.x * gm, q.y * gm, q.z * gm, q.w * gm);
  }
  const float r_t = rets[b * NA + r];   // used only by h==0 threads
  const float av  = fabsf(alpha[b]);

  float w_t = 1.0f / NA;
  if (tid < NA) ws[tid] = w_t;
  __syncthreads();

  float v_t = 0.0f;

#pragma unroll 1
  for (int it = 0; it < NIT; ++it) {
    // ---- 1. half-row dot: partial = A[r][64h..] . w[64h..] ----
    const float4* ws4 = reinterpret_cast<const float4*>(ws) + 16 * h;
    float4 acc = make_float4(0.f, 0.f, 0.f, 0.f);
#pragma unroll
    for (int k = 0; k < 16; ++k) {
      float4 wk = ws4[k];  // wave-uniform address -> broadcast ds_read_b128
      acc.x = fmaf(a[k].x, wk.x, acc.x);
      acc.y = fmaf(a[k].y, wk.y, acc.y);
      acc.z = fmaf(a[k].z, wk.z, acc.z);
      acc.w = fmaf(a[k].w, wk.w, acc.w);
    }
    partial[tid] = (acc.x + acc.y) + (acc.z + acc.w);
    __syncthreads();

    // ---- 2. combine halves; risk & norm reductions (threads 0..127) ----
    float Aw = 0.0f;
    if (tid < NA) {
      Aw = partial[tid] + partial[tid + NA];
      float p1 = wave_sum64(w_t * Aw);
      float p2 = wave_sum64(w_t * w_t);
      if (lane == 63) { pp[wv * 2 + 0] = p1; pp[wv * 2 + 1] = p2; }
    }
    __syncthreads();

    // ---- 3. gradient step + min/max for bisection bracket ----
    if (tid < NA) {
      const float risk = sqrtf(pp[0] + pp[2] + EPSC);
      const float nrm  = sqrtf(pp[1] + pp[3] + EPSC);
      const float g_t  = r_t - Aw / risk - av * (w_t / nrm);
      v_t = w_t + LRC * g_t;
      vs[tid] = v_t;
      float mn = wave_min64(v_t);
      float mx = wave_max64(v_t);
      if (lane == 63) { pp[4 + wv] = mn; pp[6 + wv] = mx; }
    }
    __syncthreads();

    // ---- 4. bisection for tau (wave 0 only; 2 elements per lane) ----
    if (wv == 0) {
      float v0 = vs[lane];
      float v1 = vs[lane + 64];
      float lo = fminf(pp[4], pp[5]) - 2.0f;  // min(v) - c - 1
      float hi = fmaxf(pp[6], pp[7]) + 1.0f;  // max(v) + c
#pragma unroll 1
      for (int rr = 0; rr < NBIS; ++rr) {
        const float mid = 0.5f * (lo + hi);
        float s = clip1(v0 - mid) + clip1(v1 - mid);
        s = wave_sum64(s);
        const float stot = read_lane63(s);
        const bool big = stot > 1.0f;
        lo = big ? mid : lo;
        hi = big ? hi : mid;
      }
      if (lane == 0) tau_s = 0.5f * (lo + hi);
    }
    __syncthreads();

    // ---- 5. project & publish new w ----
    if (tid < NA) {
      w_t = clip1(v_t - tau_s);
      ws[tid] = w_t;
    }
    __syncthreads();
  }

  if (tid < NA) out[b * NA + tid] = w_t;
}

extern "C" void kernel_launch(void* const* d_in, const int* in_sizes, int n_in,
                              void* d_out, int out_size, void* d_ws, size_t ws_size,
                              hipStream_t stream) {
  const float* rets   = (const float*)d_in[0];
  const float* covmat = (const float*)d_in[1];
  const float* gamma  = (const float*)d_in[2];
  const float* alpha  = (const float*)d_in[3];
  float* out = (float*)d_out;

  hipLaunchKernelGGL(markowitz_kernel, dim3(NBATCH), dim3(NTHR), 0, stream,
                     rets, covmat, gamma, alpha, out);
}